// Round 6
// baseline (589.103 us; speedup 1.0000x reference)
//
#include <hip/hip_runtime.h>
#include <hip/hip_bf16.h>

// BoostedCausalAttention baseline: bf16 MFMA pipeline
// B=2 T=2048 D=1024 H=16 DH=64, fp32 in/out, bf16 internal compute.
// R1 fix: attention grid covered only T/2 rows (16 tiles of 64); now 32.
// R2-R5: identical resubmits — bench died on UnresponsiveContainer (infra,
// same dead pod each time; kernel never executed). R5 added a full offline
// layout/index audit (no bugs found).

typedef __bf16 bf16x8 __attribute__((ext_vector_type(8)));
typedef float f32x4 __attribute__((ext_vector_type(4)));

__device__ __forceinline__ unsigned short f2bf(float f) {
  union { __hip_bfloat16 h; unsigned short u; } cv;
  cv.h = __float2bfloat16(f);
  return cv.u;
}

#define GLD16(gp, lp) __builtin_amdgcn_global_load_lds(                      \
    (const __attribute__((address_space(1))) void*)(gp),                     \
    (__attribute__((address_space(3))) void*)(lp), 16, 0, 0)

// ---------------- transpose + cast: fp32 [R][C] -> bf16 [C][R] --------------
__global__ __launch_bounds__(256) void transpose_cast(
    const float* __restrict__ in, __hip_bfloat16* __restrict__ out, int R, int C) {
  __shared__ float t[32][33];
  int bx = blockIdx.x * 32, by = blockIdx.y * 32;
  int tx = threadIdx.x, ty = threadIdx.y;
#pragma unroll
  for (int i = 0; i < 32; i += 8)
    t[ty + i][tx] = in[(size_t)(by + ty + i) * C + bx + tx];
  __syncthreads();
#pragma unroll
  for (int i = 0; i < 32; i += 8)
    out[(size_t)(bx + ty + i) * R + by + tx] = __float2bfloat16(t[tx][ty + i]);
}

// ---------------- cast x -> bf16 (vec4) ------------------------------------
__global__ __launch_bounds__(256) void cast_f32_bf16(
    const float* __restrict__ in, __hip_bfloat16* __restrict__ out) {
  size_t e = ((size_t)blockIdx.x * blockDim.x + threadIdx.x) * 4;
  float4 v = *(const float4*)(in + e);
  ushort4 o;
  o.x = f2bf(v.x); o.y = f2bf(v.y); o.z = f2bf(v.z); o.w = f2bf(v.w);
  *(ushort4*)((unsigned short*)out + e) = o;
}

// --- catb[:, :1024] = bf16(pred); residb = bf16(x - pred) -------------------
__global__ __launch_bounds__(256) void resid_cast(
    const float* __restrict__ x, const float* __restrict__ pred,
    __hip_bfloat16* __restrict__ catb, __hip_bfloat16* __restrict__ residb) {
  size_t e = ((size_t)blockIdx.x * blockDim.x + threadIdx.x) * 4;
  float4 xv = *(const float4*)(x + e);
  float4 pv = *(const float4*)(pred + e);
  size_t row = e >> 10, col = e & 1023;
  ushort4 pb, rb;
  pb.x = f2bf(pv.x); pb.y = f2bf(pv.y); pb.z = f2bf(pv.z); pb.w = f2bf(pv.w);
  rb.x = f2bf(xv.x - pv.x); rb.y = f2bf(xv.y - pv.y);
  rb.z = f2bf(xv.z - pv.z); rb.w = f2bf(xv.w - pv.w);
  *(ushort4*)((unsigned short*)catb + row * 2048 + col) = pb;
  *(ushort4*)((unsigned short*)residb + e) = rb;
}

// --- catb[:, 1024:] = bf16(corr) --------------------------------------------
__global__ __launch_bounds__(256) void corr_cast(
    const float* __restrict__ corr, __hip_bfloat16* __restrict__ catb) {
  size_t e = ((size_t)blockIdx.x * blockDim.x + threadIdx.x) * 4;
  float4 v = *(const float4*)(corr + e);
  size_t row = e >> 10, col = e & 1023;
  ushort4 o;
  o.x = f2bf(v.x); o.y = f2bf(v.y); o.z = f2bf(v.z); o.w = f2bf(v.w);
  *(ushort4*)((unsigned short*)catb + row * 2048 + 1024 + col) = o;
}

// ---------------- bf16 MFMA GEMM, 128x128 tile, BK=32 (m97 structure) -------
// A [M][K] bf16 row-major, Bt [N][K] bf16 row-major, bias fp32 [N].
// EPI 0: out bf16 = acc + bias
// EPI 1: out bf16 = sigmoid(acc+bias) * aux0 + aux1   (aux fp32 [M][N])
// EPI 2: out fp32 = acc + bias
template <int EPI>
__global__ __launch_bounds__(256) void gemm_bf16(
    const __hip_bfloat16* __restrict__ A, const __hip_bfloat16* __restrict__ Bt,
    const float* __restrict__ bias, void* __restrict__ outp,
    const float* __restrict__ aux0, const float* __restrict__ aux1,
    int M, int N, int K) {
  __shared__ __hip_bfloat16 As[128 * 32];
  __shared__ __hip_bfloat16 Bs[128 * 32];
  const int tid = threadIdx.x;
  const int lane = tid & 63, wid = tid >> 6;
  const int wr = wid >> 1, wc = wid & 1;
  const int lr = lane & 15, lk = (lane >> 4) * 8;
  const size_t brow = (size_t)blockIdx.y * 128, bcol = (size_t)blockIdx.x * 128;
  f32x4 acc[4][4] = {};
  for (int k0 = 0; k0 < K; k0 += 32) {
#pragma unroll
    for (int r = 0; r < 2; ++r) {
      int c = tid + r * 256;  // 512 chunks of 16B per 128x32 tile
      GLD16(A + (brow + (size_t)(c >> 2)) * K + k0 + (c & 3) * 8,
            (__hip_bfloat16*)As + c * 8);
      GLD16(Bt + (bcol + (size_t)(c >> 2)) * K + k0 + (c & 3) * 8,
            (__hip_bfloat16*)Bs + c * 8);
    }
    __syncthreads();
    bf16x8 a[4], b[4];
#pragma unroll
    for (int m = 0; m < 4; ++m)
      a[m] = *(const bf16x8*)(As + (wr * 64 + m * 16 + lr) * 32 + lk);
#pragma unroll
    for (int n = 0; n < 4; ++n)
      b[n] = *(const bf16x8*)(Bs + (wc * 64 + n * 16 + lr) * 32 + lk);
#pragma unroll
    for (int m = 0; m < 4; ++m)
#pragma unroll
      for (int n = 0; n < 4; ++n)
        acc[m][n] = __builtin_amdgcn_mfma_f32_16x16x32_bf16(a[m], b[n], acc[m][n], 0, 0, 0);
    __syncthreads();
  }
  const int r0 = (lane >> 4) * 4, cn = lane & 15;
#pragma unroll
  for (int m = 0; m < 4; ++m)
#pragma unroll
    for (int n = 0; n < 4; ++n) {
      size_t col = bcol + wc * 64 + n * 16 + cn;
      float bv = bias[col];
#pragma unroll
      for (int j = 0; j < 4; ++j) {
        size_t row = brow + wr * 64 + m * 16 + r0 + j;
        float v = acc[m][n][j] + bv;
        if constexpr (EPI == 0) {
          ((__hip_bfloat16*)outp)[row * N + col] = __float2bfloat16(v);
        } else if constexpr (EPI == 1) {
          float g = 1.0f / (1.0f + __expf(-v));
          float val = g * aux0[row * N + col] + aux1[row * N + col];
          ((__hip_bfloat16*)outp)[row * N + col] = __float2bfloat16(val);
        } else {
          ((float*)outp)[row * N + col] = v;
        }
      }
    }
}

// ---------------- causal flash attention -----------------------------------
// qkv bf16 [B*T][3*1024] (q at col 0, k at 1024, v at 2048; per-head 64 cols)
// 4 waves/block; wave w owns 16 q-rows of a 64-row q-tile; KV tiles of 64.
__global__ __launch_bounds__(256) void attn_kernel(
    const __hip_bfloat16* __restrict__ qkv, float* __restrict__ outp) {
  const int b = blockIdx.z, h = blockIdx.y, qt = blockIdx.x;
  const int q0 = qt * 64;
  __shared__ __hip_bfloat16 qs[64 * 64];
  __shared__ __hip_bfloat16 ks[64 * 64];
  __shared__ __hip_bfloat16 vts[64 * 64];   // V^T: [dh][kv]
  __shared__ __hip_bfloat16 ps[4][16 * 64]; // per-wave P
  const int tid = threadIdx.x, lane = tid & 63, w = tid >> 6;
  const int lr = lane & 15, lg = lane >> 4;
  const size_t rs = 3072;
  const __hip_bfloat16* qb = qkv + ((size_t)b * 2048 + q0) * rs + h * 64;
  const __hip_bfloat16* kb = qkv + (size_t)b * 2048 * rs + 1024 + h * 64;
  const __hip_bfloat16* vb = qkv + (size_t)b * 2048 * rs + 2048 + h * 64;
#pragma unroll
  for (int r = 0; r < 2; ++r) {  // stage Q tile [64][64]
    int c = tid + r * 256;
    GLD16(qb + (size_t)(c >> 3) * rs + (c & 7) * 8, qs + c * 8);
  }
  float m_run[4] = {-1e30f, -1e30f, -1e30f, -1e30f};
  float l_run[4] = {0.f, 0.f, 0.f, 0.f};
  f32x4 o[4] = {};
  for (int kvt = 0; kvt <= qt; ++kvt) {
    const int kv0 = kvt * 64;
#pragma unroll
    for (int r = 0; r < 2; ++r) {  // stage K tile [64][64] (== Bt layout)
      int c = tid + r * 256;
      GLD16(kb + (size_t)(kv0 + (c >> 3)) * rs + (c & 7) * 8, ks + c * 8);
    }
#pragma unroll
    for (int r = 0; r < 2; ++r) {  // stage V transposed
      int c = tid + r * 256;
      int row = c >> 3, seg = c & 7;
      float4 vv = *(const float4*)(vb + (size_t)(kv0 + row) * rs + seg * 8);
      const __hip_bfloat16* e8 = (const __hip_bfloat16*)&vv;
#pragma unroll
      for (int i = 0; i < 8; ++i) vts[(seg * 8 + i) * 64 + row] = e8[i];
    }
    __syncthreads();
    bf16x8 qa0 = *(const bf16x8*)(qs + (w * 16 + lr) * 64 + lg * 8);
    bf16x8 qa1 = *(const bf16x8*)(qs + (w * 16 + lr) * 64 + 32 + lg * 8);
    f32x4 s4[4] = {};
#pragma unroll
    for (int n = 0; n < 4; ++n) {  // S = Q K^T
      bf16x8 k0f = *(const bf16x8*)(ks + (n * 16 + lr) * 64 + lg * 8);
      bf16x8 k1f = *(const bf16x8*)(ks + (n * 16 + lr) * 64 + 32 + lg * 8);
      s4[n] = __builtin_amdgcn_mfma_f32_16x16x32_bf16(qa0, k0f, s4[n], 0, 0, 0);
      s4[n] = __builtin_amdgcn_mfma_f32_16x16x32_bf16(qa1, k1f, s4[n], 0, 0, 0);
    }
    const bool diag = (kvt == qt);
    float p[4][4], mloc[4];
#pragma unroll
    for (int j = 0; j < 4; ++j) {
      float mm = -1e30f;
#pragma unroll
      for (int n = 0; n < 4; ++n) {
        float v = s4[n][j] * 0.125f;
        if (diag && (n * 16 + lr) > (w * 16 + lg * 4 + j)) v = -1e30f;
        p[n][j] = v;
        mm = fmaxf(mm, v);
      }
      mloc[j] = mm;
    }
#pragma unroll
    for (int off = 1; off < 16; off <<= 1)
#pragma unroll
      for (int j = 0; j < 4; ++j)
        mloc[j] = fmaxf(mloc[j], __shfl_xor(mloc[j], off, 16));
    float sc[4], ls[4];
#pragma unroll
    for (int j = 0; j < 4; ++j) {
      float mn = fmaxf(m_run[j], mloc[j]);
      sc[j] = __expf(m_run[j] - mn);
      m_run[j] = mn;
      float s = 0.f;
#pragma unroll
      for (int n = 0; n < 4; ++n) { p[n][j] = __expf(p[n][j] - mn); s += p[n][j]; }
      ls[j] = s;
    }
#pragma unroll
    for (int off = 1; off < 16; off <<= 1)
#pragma unroll
      for (int j = 0; j < 4; ++j) ls[j] += __shfl_xor(ls[j], off, 16);
#pragma unroll
    for (int j = 0; j < 4; ++j) l_run[j] = l_run[j] * sc[j] + ls[j];
#pragma unroll
    for (int n = 0; n < 4; ++n)
#pragma unroll
      for (int j = 0; j < 4; ++j) o[n][j] *= sc[j];
    // P (S-layout) -> wave-private LDS -> A-operand layout
#pragma unroll
    for (int n = 0; n < 4; ++n)
#pragma unroll
      for (int j = 0; j < 4; ++j)
        ps[w][(lg * 4 + j) * 64 + n * 16 + lr] = __float2bfloat16(p[n][j]);
    bf16x8 pa0 = *(const bf16x8*)(&ps[w][lr * 64 + lg * 8]);
    bf16x8 pa1 = *(const bf16x8*)(&ps[w][lr * 64 + 32 + lg * 8]);
#pragma unroll
    for (int n = 0; n < 4; ++n) {  // O += P V
      bf16x8 v0f = *(const bf16x8*)(vts + (n * 16 + lr) * 64 + lg * 8);
      bf16x8 v1f = *(const bf16x8*)(vts + (n * 16 + lr) * 64 + 32 + lg * 8);
      o[n] = __builtin_amdgcn_mfma_f32_16x16x32_bf16(pa0, v0f, o[n], 0, 0, 0);
      o[n] = __builtin_amdgcn_mfma_f32_16x16x32_bf16(pa1, v1f, o[n], 0, 0, 0);
    }
    __syncthreads();
  }
#pragma unroll
  for (int j = 0; j < 4; ++j) {
    float inv = 1.0f / l_run[j];
    size_t row = (size_t)b * 2048 + q0 + w * 16 + lg * 4 + j;
#pragma unroll
    for (int n = 0; n < 4; ++n)
      outp[row * 1024 + h * 64 + n * 16 + lr] = o[n][j] * inv;
  }
}

extern "C" void kernel_launch(void* const* d_in, const int* in_sizes, int n_in,
                              void* d_out, int out_size, void* d_ws, size_t ws_size,
                              hipStream_t stream) {
  const float* x     = (const float*)d_in[0];
  const float* Wqkv0 = (const float*)d_in[1];
  const float* bqkv0 = (const float*)d_in[2];
  const float* Wqkv1 = (const float*)d_in[3];
  const float* bqkv1 = (const float*)d_in[4];
  const float* Wg    = (const float*)d_in[5];
  const float* bg    = (const float*)d_in[6];
  const float* Wo    = (const float*)d_in[7];
  const float* bo    = (const float*)d_in[8];
  float* out = (float*)d_out;

  char* ws = (char*)d_ws;
  __hip_bfloat16* xb   = (__hip_bfloat16*)(ws);              // 8 MB (x_bf16 -> residb -> preout)
  __hip_bfloat16* qkv  = (__hip_bfloat16*)(ws + 8388608);    // 24 MB (qkv0 then qkv1)
  float*          pred = (float*)(ws + 33554432);            // 16 MB
  float*          corr = (float*)(ws + 50331648);            // 16 MB
  __hip_bfloat16* catb = (__hip_bfloat16*)(ws + 67108864);   // 16 MB [pred | corr] bf16
  __hip_bfloat16* Wt0  = (__hip_bfloat16*)(ws + 83886080);   // 6 MB
  __hip_bfloat16* Wt1  = (__hip_bfloat16*)(ws + 90177536);   // 6 MB
  __hip_bfloat16* Wgt  = (__hip_bfloat16*)(ws + 96468992);   // 4 MB
  __hip_bfloat16* Wot  = (__hip_bfloat16*)(ws + 100663296);  // 2 MB  (total ~98 MB)

  dim3 tb(32, 8);
  transpose_cast<<<dim3(3072 / 32, 1024 / 32), tb, 0, stream>>>(Wqkv0, Wt0, 1024, 3072);
  transpose_cast<<<dim3(3072 / 32, 1024 / 32), tb, 0, stream>>>(Wqkv1, Wt1, 1024, 3072);
  transpose_cast<<<dim3(1024 / 32, 2048 / 32), tb, 0, stream>>>(Wg, Wgt, 2048, 1024);
  transpose_cast<<<dim3(1024 / 32, 1024 / 32), tb, 0, stream>>>(Wo, Wot, 1024, 1024);
  cast_f32_bf16<<<4096, 256, 0, stream>>>(x, xb);

  // qkv0 = x @ Wqkv0 + b
  gemm_bf16<0><<<dim3(24, 32), 256, 0, stream>>>(xb, Wt0, bqkv0, (void*)qkv,
                                                 nullptr, nullptr, 4096, 3072, 1024);
  attn_kernel<<<dim3(32, 16, 2), 256, 0, stream>>>(qkv, pred);
  resid_cast<<<4096, 256, 0, stream>>>(x, pred, catb, xb);
  // qkv1 = (x - pred) @ Wqkv1 + b
  gemm_bf16<0><<<dim3(24, 32), 256, 0, stream>>>(xb, Wt1, bqkv1, (void*)qkv,
                                                 nullptr, nullptr, 4096, 3072, 1024);
  attn_kernel<<<dim3(32, 16, 2), 256, 0, stream>>>(qkv, corr);
  corr_cast<<<4096, 256, 0, stream>>>(corr, catb);
  // preout = sigmoid(cat @ Wg + bg) * corr + pred   (into xb)
  gemm_bf16<1><<<dim3(8, 32), 256, 0, stream>>>(catb, Wgt, bg, (void*)xb,
                                                corr, pred, 4096, 1024, 2048);
  // out = preout @ Wo + bo (fp32)
  gemm_bf16<2><<<dim3(8, 32), 256, 0, stream>>>(xb, Wot, bo, (void*)out,
                                                nullptr, nullptr, 4096, 1024, 1024);
}

// Round 8
// 474.981 us; speedup vs baseline: 1.2403x; 1.2403x over previous
//
#include <hip/hip_runtime.h>
#include <hip/hip_bf16.h>

// BoostedCausalAttention: bf16 MFMA pipeline
// B=2 T=2048 D=1024 H=16 DH=64, fp32 in/out, bf16 internal compute.
// R6 (verified): baseline 589us; attn 2x213us, MfmaUtil 3.3%, 3.35e7 LDS
//   bank conflicts/dispatch (~25% of cycles), rest stall-bound.
// R7: attention V2 = (a) XOR swizzle on qs/ks (pre-swizzled gload source,
//   rule #21), vts (write+read swizzle), ps; (b) K/V double-buffer 2-phase
//   (issue next-tile loads before compute, V regs->LDS after compute);
//   (c) Q fragments hoisted out of the KV loop.
// R8: identical resubmit (infra UnresponsiveContainer, same dead pod);
//   offline re-audit: all swizzles bijective; b128 wave64 floor = 8
//   lanes/bank-group, V2 reads hit the floor.

typedef __bf16 bf16x8 __attribute__((ext_vector_type(8)));
typedef float f32x4 __attribute__((ext_vector_type(4)));

__device__ __forceinline__ unsigned short f2bf(float f) {
  union { __hip_bfloat16 h; unsigned short u; } cv;
  cv.h = __float2bfloat16(f);
  return cv.u;
}

#define GLD16(gp, lp) __builtin_amdgcn_global_load_lds(                      \
    (const __attribute__((address_space(1))) void*)(gp),                     \
    (__attribute__((address_space(3))) void*)(lp), 16, 0, 0)

// ---------------- transpose + cast: fp32 [R][C] -> bf16 [C][R] --------------
__global__ __launch_bounds__(256) void transpose_cast(
    const float* __restrict__ in, __hip_bfloat16* __restrict__ out, int R, int C) {
  __shared__ float t[32][33];
  int bx = blockIdx.x * 32, by = blockIdx.y * 32;
  int tx = threadIdx.x, ty = threadIdx.y;
#pragma unroll
  for (int i = 0; i < 32; i += 8)
    t[ty + i][tx] = in[(size_t)(by + ty + i) * C + bx + tx];
  __syncthreads();
#pragma unroll
  for (int i = 0; i < 32; i += 8)
    out[(size_t)(bx + ty + i) * R + by + tx] = __float2bfloat16(t[tx][ty + i]);
}

// ---------------- cast x -> bf16 (vec4) ------------------------------------
__global__ __launch_bounds__(256) void cast_f32_bf16(
    const float* __restrict__ in, __hip_bfloat16* __restrict__ out) {
  size_t e = ((size_t)blockIdx.x * blockDim.x + threadIdx.x) * 4;
  float4 v = *(const float4*)(in + e);
  ushort4 o;
  o.x = f2bf(v.x); o.y = f2bf(v.y); o.z = f2bf(v.z); o.w = f2bf(v.w);
  *(ushort4*)((unsigned short*)out + e) = o;
}

// --- catb[:, :1024] = bf16(pred); residb = bf16(x - pred) -------------------
__global__ __launch_bounds__(256) void resid_cast(
    const float* __restrict__ x, const float* __restrict__ pred,
    __hip_bfloat16* __restrict__ catb, __hip_bfloat16* __restrict__ residb) {
  size_t e = ((size_t)blockIdx.x * blockDim.x + threadIdx.x) * 4;
  float4 xv = *(const float4*)(x + e);
  float4 pv = *(const float4*)(pred + e);
  size_t row = e >> 10, col = e & 1023;
  ushort4 pb, rb;
  pb.x = f2bf(pv.x); pb.y = f2bf(pv.y); pb.z = f2bf(pv.z); pb.w = f2bf(pv.w);
  rb.x = f2bf(xv.x - pv.x); rb.y = f2bf(xv.y - pv.y);
  rb.z = f2bf(xv.z - pv.z); rb.w = f2bf(xv.w - pv.w);
  *(ushort4*)((unsigned short*)catb + row * 2048 + col) = pb;
  *(ushort4*)((unsigned short*)residb + e) = rb;
}

// --- catb[:, 1024:] = bf16(corr) --------------------------------------------
__global__ __launch_bounds__(256) void corr_cast(
    const float* __restrict__ corr, __hip_bfloat16* __restrict__ catb) {
  size_t e = ((size_t)blockIdx.x * blockDim.x + threadIdx.x) * 4;
  float4 v = *(const float4*)(corr + e);
  size_t row = e >> 10, col = e & 1023;
  ushort4 o;
  o.x = f2bf(v.x); o.y = f2bf(v.y); o.z = f2bf(v.z); o.w = f2bf(v.w);
  *(ushort4*)((unsigned short*)catb + row * 2048 + 1024 + col) = o;
}

// ---------------- bf16 MFMA GEMM, 128x128 tile, BK=32 (m97 structure) -------
template <int EPI>
__global__ __launch_bounds__(256) void gemm_bf16(
    const __hip_bfloat16* __restrict__ A, const __hip_bfloat16* __restrict__ Bt,
    const float* __restrict__ bias, void* __restrict__ outp,
    const float* __restrict__ aux0, const float* __restrict__ aux1,
    int M, int N, int K) {
  __shared__ __hip_bfloat16 As[128 * 32];
  __shared__ __hip_bfloat16 Bs[128 * 32];
  const int tid = threadIdx.x;
  const int lane = tid & 63, wid = tid >> 6;
  const int wr = wid >> 1, wc = wid & 1;
  const int lr = lane & 15, lk = (lane >> 4) * 8;
  const size_t brow = (size_t)blockIdx.y * 128, bcol = (size_t)blockIdx.x * 128;
  f32x4 acc[4][4] = {};
  for (int k0 = 0; k0 < K; k0 += 32) {
#pragma unroll
    for (int r = 0; r < 2; ++r) {
      int c = tid + r * 256;  // 512 chunks of 16B per 128x32 tile
      GLD16(A + (brow + (size_t)(c >> 2)) * K + k0 + (c & 3) * 8,
            (__hip_bfloat16*)As + c * 8);
      GLD16(Bt + (bcol + (size_t)(c >> 2)) * K + k0 + (c & 3) * 8,
            (__hip_bfloat16*)Bs + c * 8);
    }
    __syncthreads();
    bf16x8 a[4], b[4];
#pragma unroll
    for (int m = 0; m < 4; ++m)
      a[m] = *(const bf16x8*)(As + (wr * 64 + m * 16 + lr) * 32 + lk);
#pragma unroll
    for (int n = 0; n < 4; ++n)
      b[n] = *(const bf16x8*)(Bs + (wc * 64 + n * 16 + lr) * 32 + lk);
#pragma unroll
    for (int m = 0; m < 4; ++m)
#pragma unroll
      for (int n = 0; n < 4; ++n)
        acc[m][n] = __builtin_amdgcn_mfma_f32_16x16x32_bf16(a[m], b[n], acc[m][n], 0, 0, 0);
    __syncthreads();
  }
  const int r0 = (lane >> 4) * 4, cn = lane & 15;
#pragma unroll
  for (int m = 0; m < 4; ++m)
#pragma unroll
    for (int n = 0; n < 4; ++n) {
      size_t col = bcol + wc * 64 + n * 16 + cn;
      float bv = bias[col];
#pragma unroll
      for (int j = 0; j < 4; ++j) {
        size_t row = brow + wr * 64 + m * 16 + r0 + j;
        float v = acc[m][n][j] + bv;
        if constexpr (EPI == 0) {
          ((__hip_bfloat16*)outp)[row * N + col] = __float2bfloat16(v);
        } else if constexpr (EPI == 1) {
          float g = 1.0f / (1.0f + __expf(-v));
          float val = g * aux0[row * N + col] + aux1[row * N + col];
          ((__hip_bfloat16*)outp)[row * N + col] = __float2bfloat16(val);
        } else {
          ((float*)outp)[row * N + col] = v;
        }
      }
    }
}

// ---------------- causal flash attention V2 ---------------------------------
// qkv bf16 [B*T][3*1024]; 4 waves/block; wave w owns 16 q-rows of a 64-row
// q-tile; KV tiles of 64, double-buffered LDS, XOR-swizzled layouts.
// Swizzles (16B-slot granularity, 8 slots per 128B row):
//   qs/ks : phys_slot = slot ^ (row & 7)   (gload_lds: linear dest,
//           pre-swizzled GLOBAL source per rule #21)
//   vts   : phys_slot = slot ^ (dh&7) ^ ((dh>>3)&7)  (reg-staged writes:
//           makes both scatter-writes and reads conflict-floor)
//   ps    : phys_slot = slot ^ (prow & 7)
__global__ __launch_bounds__(256) void attn_kernel(
    const __hip_bfloat16* __restrict__ qkv, float* __restrict__ outp) {
  const int b = blockIdx.z, h = blockIdx.y, qt = blockIdx.x;
  const int q0 = qt * 64;
  __shared__ __hip_bfloat16 qs[64 * 64];
  __shared__ __hip_bfloat16 ks[2][64 * 64];
  __shared__ __hip_bfloat16 vts[2][64 * 64];  // V^T: [dh][kv], swizzled
  __shared__ __hip_bfloat16 ps[4][16 * 64];   // per-wave P, swizzled
  const int tid = threadIdx.x, lane = tid & 63, w = tid >> 6;
  const int lr = lane & 15, lg = lane >> 4;
  const int sw = lr & 7;  // read-swizzle for qs/ks/ps rows (row&7 == lr&7)
  const size_t rs = 3072;
  const __hip_bfloat16* qb = qkv + ((size_t)b * 2048 + q0) * rs + h * 64;
  const __hip_bfloat16* kb = qkv + (size_t)b * 2048 * rs + 1024 + h * 64;
  const __hip_bfloat16* vb = qkv + (size_t)b * 2048 * rs + 2048 + h * 64;

  float4 vreg[2];
  // ---- prologue: stage Q + K0 (gload_lds, pre-swizzled src), V0 -> regs
#pragma unroll
  for (int r = 0; r < 2; ++r) {
    int c = tid + r * 256, row = c >> 3, p = c & 7;
    GLD16(qb + (size_t)row * rs + (p ^ (row & 7)) * 8, qs + c * 8);
    GLD16(kb + (size_t)row * rs + (p ^ (row & 7)) * 8, ks[0] + c * 8);
    vreg[r] = *(const float4*)(vb + (size_t)row * rs + p * 8);
  }
  __syncthreads();  // Q/K0 visible (barrier drains vmcnt)
  // hoist Q fragments (loop-invariant)
  const int qrow = w * 16 + lr;
  const bf16x8 qa0 = *(const bf16x8*)(qs + qrow * 64 + ((lg) ^ (qrow & 7)) * 8);
  const bf16x8 qa1 = *(const bf16x8*)(qs + qrow * 64 + ((4 + lg) ^ (qrow & 7)) * 8);
  // write V0 (transpose, swizzled)
#pragma unroll
  for (int r = 0; r < 2; ++r) {
    int c = tid + r * 256, row = c >> 3, seg = c & 7;
    const __hip_bfloat16* e8 = (const __hip_bfloat16*)&vreg[r];
#pragma unroll
    for (int i = 0; i < 8; ++i)
      vts[0][(seg * 8 + i) * 64 + (((row >> 3) ^ i ^ seg)) * 8 + (row & 7)] = e8[i];
  }
  __syncthreads();  // vts[0] visible

  float m_run[4] = {-1e30f, -1e30f, -1e30f, -1e30f};
  float l_run[4] = {0.f, 0.f, 0.f, 0.f};
  f32x4 o[4] = {};
  int cur = 0;
  for (int kvt = 0; kvt <= qt; ++kvt) {
    const int nxt = cur ^ 1;
    const bool pf = (kvt < qt);
    if (pf) {  // issue next-tile loads FIRST (overlap with compute below)
      const int kv1 = (kvt + 1) * 64;
#pragma unroll
      for (int r = 0; r < 2; ++r) {
        int c = tid + r * 256, row = c >> 3, p = c & 7;
        GLD16(kb + (size_t)(kv1 + row) * rs + (p ^ (row & 7)) * 8, ks[nxt] + c * 8);
        vreg[r] = *(const float4*)(vb + (size_t)(kv1 + row) * rs + p * 8);
      }
    }
    // ---- S = Q K^T on ks[cur]
    f32x4 s4[4] = {};
#pragma unroll
    for (int n = 0; n < 4; ++n) {
      const int kr = n * 16 + lr;
      bf16x8 k0f = *(const bf16x8*)(ks[cur] + kr * 64 + ((lg) ^ sw) * 8);
      bf16x8 k1f = *(const bf16x8*)(ks[cur] + kr * 64 + ((4 + lg) ^ sw) * 8);
      s4[n] = __builtin_amdgcn_mfma_f32_16x16x32_bf16(qa0, k0f, s4[n], 0, 0, 0);
      s4[n] = __builtin_amdgcn_mfma_f32_16x16x32_bf16(qa1, k1f, s4[n], 0, 0, 0);
    }
    // ---- online softmax (wave-parallel over 16-lane groups)
    const bool diag = (kvt == qt);
    float p[4][4], mloc[4];
#pragma unroll
    for (int j = 0; j < 4; ++j) {
      float mm = -1e30f;
#pragma unroll
      for (int n = 0; n < 4; ++n) {
        float v = s4[n][j] * 0.125f;
        if (diag && (n * 16 + lr) > (w * 16 + lg * 4 + j)) v = -1e30f;
        p[n][j] = v;
        mm = fmaxf(mm, v);
      }
      mloc[j] = mm;
    }
#pragma unroll
    for (int off = 1; off < 16; off <<= 1)
#pragma unroll
      for (int j = 0; j < 4; ++j)
        mloc[j] = fmaxf(mloc[j], __shfl_xor(mloc[j], off, 16));
    float sc[4], ls[4];
#pragma unroll
    for (int j = 0; j < 4; ++j) {
      float mn = fmaxf(m_run[j], mloc[j]);
      sc[j] = __expf(m_run[j] - mn);
      m_run[j] = mn;
      float s = 0.f;
#pragma unroll
      for (int n = 0; n < 4; ++n) { p[n][j] = __expf(p[n][j] - mn); s += p[n][j]; }
      ls[j] = s;
    }
#pragma unroll
    for (int off = 1; off < 16; off <<= 1)
#pragma unroll
      for (int j = 0; j < 4; ++j) ls[j] += __shfl_xor(ls[j], off, 16);
#pragma unroll
    for (int j = 0; j < 4; ++j) l_run[j] = l_run[j] * sc[j] + ls[j];
#pragma unroll
    for (int n = 0; n < 4; ++n)
#pragma unroll
      for (int j = 0; j < 4; ++j) o[n][j] *= sc[j];
    // ---- P (C-layout) -> wave-private LDS (swizzled) -> A-operand layout
#pragma unroll
    for (int n = 0; n < 4; ++n)
#pragma unroll
      for (int j = 0; j < 4; ++j) {
        const int prow = lg * 4 + j;
        const int phys = (n * 2 + (lr >> 3)) ^ (prow & 7);
        ps[w][prow * 64 + phys * 8 + (lr & 7)] = __float2bfloat16(p[n][j]);
      }
    bf16x8 pa0 = *(const bf16x8*)(&ps[w][lr * 64 + ((lg) ^ sw) * 8]);
    bf16x8 pa1 = *(const bf16x8*)(&ps[w][lr * 64 + ((4 + lg) ^ sw) * 8]);
    // ---- O += P V on vts[cur]
#pragma unroll
    for (int n = 0; n < 4; ++n) {
      const int vdh = n * 16 + lr;
      const int swv = (vdh & 7) ^ ((vdh >> 3) & 7);
      bf16x8 v0f = *(const bf16x8*)(vts[cur] + vdh * 64 + ((lg) ^ swv) * 8);
      bf16x8 v1f = *(const bf16x8*)(vts[cur] + vdh * 64 + ((4 + lg) ^ swv) * 8);
      o[n] = __builtin_amdgcn_mfma_f32_16x16x32_bf16(pa0, v0f, o[n], 0, 0, 0);
      o[n] = __builtin_amdgcn_mfma_f32_16x16x32_bf16(pa1, v1f, o[n], 0, 0, 0);
    }
    // ---- write V(t+1) regs -> vts[nxt] (vmcnt wait lands here, after compute)
    if (pf) {
#pragma unroll
      for (int r = 0; r < 2; ++r) {
        int c = tid + r * 256, row = c >> 3, seg = c & 7;
        const __hip_bfloat16* e8 = (const __hip_bfloat16*)&vreg[r];
#pragma unroll
        for (int i = 0; i < 8; ++i)
          vts[nxt][(seg * 8 + i) * 64 + (((row >> 3) ^ i ^ seg)) * 8 + (row & 7)] = e8[i];
      }
    }
    __syncthreads();  // ks[nxt]/vts[nxt] ready; ks/vts[cur] free for overwrite
    cur = nxt;
  }
#pragma unroll
  for (int j = 0; j < 4; ++j) {
    float inv = 1.0f / l_run[j];
    size_t row = (size_t)b * 2048 + q0 + w * 16 + lg * 4 + j;
#pragma unroll
    for (int n = 0; n < 4; ++n)
      outp[row * 1024 + h * 64 + n * 16 + lr] = o[n][j] * inv;
  }
}

extern "C" void kernel_launch(void* const* d_in, const int* in_sizes, int n_in,
                              void* d_out, int out_size, void* d_ws, size_t ws_size,
                              hipStream_t stream) {
  const float* x     = (const float*)d_in[0];
  const float* Wqkv0 = (const float*)d_in[1];
  const float* bqkv0 = (const float*)d_in[2];
  const float* Wqkv1 = (const float*)d_in[3];
  const float* bqkv1 = (const float*)d_in[4];
  const float* Wg    = (const float*)d_in[5];
  const float* bg    = (const float*)d_in[6];
  const float* Wo    = (const float*)d_in[7];
  const float* bo    = (const float*)d_in[8];
  float* out = (float*)d_out;

  char* ws = (char*)d_ws;
  __hip_bfloat16* xb   = (__hip_bfloat16*)(ws);              // 8 MB (x_bf16 -> residb -> preout)
  __hip_bfloat16* qkv  = (__hip_bfloat16*)(ws + 8388608);    // 24 MB (qkv0 then qkv1)
  float*          pred = (float*)(ws + 33554432);            // 16 MB
  float*          corr = (float*)(ws + 50331648);            // 16 MB
  __hip_bfloat16* catb = (__hip_bfloat16*)(ws + 67108864);   // 16 MB [pred | corr] bf16
  __hip_bfloat16* Wt0  = (__hip_bfloat16*)(ws + 83886080);   // 6 MB
  __hip_bfloat16* Wt1  = (__hip_bfloat16*)(ws + 90177536);   // 6 MB
  __hip_bfloat16* Wgt  = (__hip_bfloat16*)(ws + 96468992);   // 4 MB
  __hip_bfloat16* Wot  = (__hip_bfloat16*)(ws + 100663296);  // 2 MB  (total ~98 MB)

  dim3 tb(32, 8);
  transpose_cast<<<dim3(3072 / 32, 1024 / 32), tb, 0, stream>>>(Wqkv0, Wt0, 1024, 3072);
  transpose_cast<<<dim3(3072 / 32, 1024 / 32), tb, 0, stream>>>(Wqkv1, Wt1, 1024, 3072);
  transpose_cast<<<dim3(1024 / 32, 2048 / 32), tb, 0, stream>>>(Wg, Wgt, 2048, 1024);
  transpose_cast<<<dim3(1024 / 32, 1024 / 32), tb, 0, stream>>>(Wo, Wot, 1024, 1024);
  cast_f32_bf16<<<4096, 256, 0, stream>>>(x, xb);

  // qkv0 = x @ Wqkv0 + b
  gemm_bf16<0><<<dim3(24, 32), 256, 0, stream>>>(xb, Wt0, bqkv0, (void*)qkv,
                                                 nullptr, nullptr, 4096, 3072, 1024);
  attn_kernel<<<dim3(32, 16, 2), 256, 0, stream>>>(qkv, pred);
  resid_cast<<<4096, 256, 0, stream>>>(x, pred, catb, xb);
  // qkv1 = (x - pred) @ Wqkv1 + b
  gemm_bf16<0><<<dim3(24, 32), 256, 0, stream>>>(xb, Wt1, bqkv1, (void*)qkv,
                                                 nullptr, nullptr, 4096, 3072, 1024);
  attn_kernel<<<dim3(32, 16, 2), 256, 0, stream>>>(qkv, corr);
  corr_cast<<<4096, 256, 0, stream>>>(corr, catb);
  // preout = sigmoid(cat @ Wg + bg) * corr + pred   (into xb)
  gemm_bf16<1><<<dim3(8, 32), 256, 0, stream>>>(catb, Wgt, bg, (void*)xb,
                                                corr, pred, 4096, 1024, 2048);
  // out = preout @ Wo + bo (fp32)
  gemm_bf16<2><<<dim3(8, 32), 256, 0, stream>>>(xb, Wot, bo, (void*)out,
                                                nullptr, nullptr, 4096, 1024, 1024);
}

// Round 9
// 352.863 us; speedup vs baseline: 1.6695x; 1.3461x over previous
//
#include <hip/hip_runtime.h>
#include <hip/hip_bf16.h>

// BoostedCausalAttention: bf16 MFMA pipeline
// B=2 T=2048 D=1024 H=16 DH=64, fp32 in/out, bf16 internal compute.
// R6 (verified): baseline 589us; attn 213us, 3.35e7 bank conflicts.
// R8 (verified): V2 swizzle+dbuf: 475us; attn 153us, conflicts 2.16e6,
//   Occupancy 11.5% (triangular-work tail), ~85% of cycles idle-stall.
// R9: causal q-tile PAIRING — block qtp handles q-tiles (qtp, 31-qtp):
//   uniform 33 tile-updates/block, staging total -26%, grid 512 = 2/CU.
//   4 waves compute BOTH q-tiles per staged KV tile (compute/tile ~2x ->
//   covers HBM latency). Q-stage LDS overlaid with ps buffers (48KB total).

typedef __bf16 bf16x8 __attribute__((ext_vector_type(8)));
typedef float f32x4 __attribute__((ext_vector_type(4)));

__device__ __forceinline__ unsigned short f2bf(float f) {
  union { __hip_bfloat16 h; unsigned short u; } cv;
  cv.h = __float2bfloat16(f);
  return cv.u;
}

#define GLD16(gp, lp) __builtin_amdgcn_global_load_lds(                      \
    (const __attribute__((address_space(1))) void*)(gp),                     \
    (__attribute__((address_space(3))) void*)(lp), 16, 0, 0)

// ---------------- transpose + cast: fp32 [R][C] -> bf16 [C][R] --------------
__global__ __launch_bounds__(256) void transpose_cast(
    const float* __restrict__ in, __hip_bfloat16* __restrict__ out, int R, int C) {
  __shared__ float t[32][33];
  int bx = blockIdx.x * 32, by = blockIdx.y * 32;
  int tx = threadIdx.x, ty = threadIdx.y;
#pragma unroll
  for (int i = 0; i < 32; i += 8)
    t[ty + i][tx] = in[(size_t)(by + ty + i) * C + bx + tx];
  __syncthreads();
#pragma unroll
  for (int i = 0; i < 32; i += 8)
    out[(size_t)(bx + ty + i) * R + by + tx] = __float2bfloat16(t[tx][ty + i]);
}

// ---------------- cast x -> bf16 (vec4) ------------------------------------
__global__ __launch_bounds__(256) void cast_f32_bf16(
    const float* __restrict__ in, __hip_bfloat16* __restrict__ out) {
  size_t e = ((size_t)blockIdx.x * blockDim.x + threadIdx.x) * 4;
  float4 v = *(const float4*)(in + e);
  ushort4 o;
  o.x = f2bf(v.x); o.y = f2bf(v.y); o.z = f2bf(v.z); o.w = f2bf(v.w);
  *(ushort4*)((unsigned short*)out + e) = o;
}

// --- catb[:, :1024] = bf16(pred); residb = bf16(x - pred) -------------------
__global__ __launch_bounds__(256) void resid_cast(
    const float* __restrict__ x, const float* __restrict__ pred,
    __hip_bfloat16* __restrict__ catb, __hip_bfloat16* __restrict__ residb) {
  size_t e = ((size_t)blockIdx.x * blockDim.x + threadIdx.x) * 4;
  float4 xv = *(const float4*)(x + e);
  float4 pv = *(const float4*)(pred + e);
  size_t row = e >> 10, col = e & 1023;
  ushort4 pb, rb;
  pb.x = f2bf(pv.x); pb.y = f2bf(pv.y); pb.z = f2bf(pv.z); pb.w = f2bf(pv.w);
  rb.x = f2bf(xv.x - pv.x); rb.y = f2bf(xv.y - pv.y);
  rb.z = f2bf(xv.z - pv.z); rb.w = f2bf(xv.w - pv.w);
  *(ushort4*)((unsigned short*)catb + row * 2048 + col) = pb;
  *(ushort4*)((unsigned short*)residb + e) = rb;
}

// --- catb[:, 1024:] = bf16(corr) --------------------------------------------
__global__ __launch_bounds__(256) void corr_cast(
    const float* __restrict__ corr, __hip_bfloat16* __restrict__ catb) {
  size_t e = ((size_t)blockIdx.x * blockDim.x + threadIdx.x) * 4;
  float4 v = *(const float4*)(corr + e);
  size_t row = e >> 10, col = e & 1023;
  ushort4 o;
  o.x = f2bf(v.x); o.y = f2bf(v.y); o.z = f2bf(v.z); o.w = f2bf(v.w);
  *(ushort4*)((unsigned short*)catb + row * 2048 + 1024 + col) = o;
}

// ---------------- bf16 MFMA GEMM, 128x128 tile, BK=32 (m97 structure) -------
template <int EPI>
__global__ __launch_bounds__(256) void gemm_bf16(
    const __hip_bfloat16* __restrict__ A, const __hip_bfloat16* __restrict__ Bt,
    const float* __restrict__ bias, void* __restrict__ outp,
    const float* __restrict__ aux0, const float* __restrict__ aux1,
    int M, int N, int K) {
  __shared__ __hip_bfloat16 As[128 * 32];
  __shared__ __hip_bfloat16 Bs[128 * 32];
  const int tid = threadIdx.x;
  const int lane = tid & 63, wid = tid >> 6;
  const int wr = wid >> 1, wc = wid & 1;
  const int lr = lane & 15, lk = (lane >> 4) * 8;
  const size_t brow = (size_t)blockIdx.y * 128, bcol = (size_t)blockIdx.x * 128;
  f32x4 acc[4][4] = {};
  for (int k0 = 0; k0 < K; k0 += 32) {
#pragma unroll
    for (int r = 0; r < 2; ++r) {
      int c = tid + r * 256;  // 512 chunks of 16B per 128x32 tile
      GLD16(A + (brow + (size_t)(c >> 2)) * K + k0 + (c & 3) * 8,
            (__hip_bfloat16*)As + c * 8);
      GLD16(Bt + (bcol + (size_t)(c >> 2)) * K + k0 + (c & 3) * 8,
            (__hip_bfloat16*)Bs + c * 8);
    }
    __syncthreads();
    bf16x8 a[4], b[4];
#pragma unroll
    for (int m = 0; m < 4; ++m)
      a[m] = *(const bf16x8*)(As + (wr * 64 + m * 16 + lr) * 32 + lk);
#pragma unroll
    for (int n = 0; n < 4; ++n)
      b[n] = *(const bf16x8*)(Bs + (wc * 64 + n * 16 + lr) * 32 + lk);
#pragma unroll
    for (int m = 0; m < 4; ++m)
#pragma unroll
      for (int n = 0; n < 4; ++n)
        acc[m][n] = __builtin_amdgcn_mfma_f32_16x16x32_bf16(a[m], b[n], acc[m][n], 0, 0, 0);
    __syncthreads();
  }
  const int r0 = (lane >> 4) * 4, cn = lane & 15;
#pragma unroll
  for (int m = 0; m < 4; ++m)
#pragma unroll
    for (int n = 0; n < 4; ++n) {
      size_t col = bcol + wc * 64 + n * 16 + cn;
      float bv = bias[col];
#pragma unroll
      for (int j = 0; j < 4; ++j) {
        size_t row = brow + wr * 64 + m * 16 + r0 + j;
        float v = acc[m][n][j] + bv;
        if constexpr (EPI == 0) {
          ((__hip_bfloat16*)outp)[row * N + col] = __float2bfloat16(v);
        } else if constexpr (EPI == 1) {
          float g = 1.0f / (1.0f + __expf(-v));
          float val = g * aux0[row * N + col] + aux1[row * N + col];
          ((__hip_bfloat16*)outp)[row * N + col] = __float2bfloat16(val);
        } else {
          ((float*)outp)[row * N + col] = v;
        }
      }
    }
}

// ---------------- causal flash attention V3 (paired q-tiles) ----------------
// qkv bf16 [B*T][3*1024]; block qtp in [0,16) handles q-tiles qlo=qtp and
// qhi=31-qtp for one (b,h). 4 waves; wave w owns rows [w*16,w*16+16) of BOTH
// tiles. KV tiles 0..qhi staged once (dbuf, swizzled); lo-tile compute active
// while kvt <= qlo. Uniform 33 tile-updates per block.
// Swizzles as R8 (verified): qs/ks slot^(row&7) via pre-swizzled gload src;
// vts slot^(dh&7)^((dh>>3)&7); ps slot^(prow&7).
// LDS: ks 16KB + vts 16KB + qps 16KB (Q staging, overlaid by ps after
// prologue; Q-frag reads drain at the __syncthreads before first ps write).
__global__ __launch_bounds__(256) void attn_kernel(
    const __hip_bfloat16* __restrict__ qkv, float* __restrict__ outp) {
  const int b = blockIdx.z, h = blockIdx.y, qtp = blockIdx.x;
  const int qlo = qtp, qhi = 31 - qtp;
  const int q0lo = qlo * 64, q0hi = qhi * 64;
  __shared__ __hip_bfloat16 ks[2][64 * 64];
  __shared__ __hip_bfloat16 vts[2][64 * 64];  // V^T [dh][kv], swizzled
  __shared__ __hip_bfloat16 qps[8192];        // Q_hi|Q_lo staging -> ps_hi|ps_lo
  const int tid = threadIdx.x, lane = tid & 63, w = tid >> 6;
  const int lr = lane & 15, lg = lane >> 4;
  const int sw = lr & 7;
  const size_t rs = 3072;
  const __hip_bfloat16* qbh = qkv + ((size_t)b * 2048 + q0hi) * rs + h * 64;
  const __hip_bfloat16* qbl = qkv + ((size_t)b * 2048 + q0lo) * rs + h * 64;
  const __hip_bfloat16* kb = qkv + (size_t)b * 2048 * rs + 1024 + h * 64;
  const __hip_bfloat16* vb = qkv + (size_t)b * 2048 * rs + 2048 + h * 64;

  float4 vreg[2];
  // ---- prologue: stage Q_hi/Q_lo/K0 (pre-swizzled src), V0 -> regs
#pragma unroll
  for (int r = 0; r < 2; ++r) {
    int c = tid + r * 256, row = c >> 3, p = c & 7;
    GLD16(qbh + (size_t)row * rs + (p ^ (row & 7)) * 8, qps + c * 8);
    GLD16(qbl + (size_t)row * rs + (p ^ (row & 7)) * 8, qps + 4096 + c * 8);
    GLD16(kb + (size_t)row * rs + (p ^ (row & 7)) * 8, ks[0] + c * 8);
    vreg[r] = *(const float4*)(vb + (size_t)row * rs + p * 8);
  }
  __syncthreads();
  const int qrow = w * 16 + lr;
  const bf16x8 qh0 = *(const bf16x8*)(qps + qrow * 64 + ((lg) ^ (qrow & 7)) * 8);
  const bf16x8 qh1 = *(const bf16x8*)(qps + qrow * 64 + ((4 + lg) ^ (qrow & 7)) * 8);
  const bf16x8 ql0 = *(const bf16x8*)(qps + 4096 + qrow * 64 + ((lg) ^ (qrow & 7)) * 8);
  const bf16x8 ql1 = *(const bf16x8*)(qps + 4096 + qrow * 64 + ((4 + lg) ^ (qrow & 7)) * 8);
  // write V0 (transpose, swizzled)
#pragma unroll
  for (int r = 0; r < 2; ++r) {
    int c = tid + r * 256, row = c >> 3, seg = c & 7;
    const __hip_bfloat16* e8 = (const __hip_bfloat16*)&vreg[r];
#pragma unroll
    for (int i = 0; i < 8; ++i)
      vts[0][(seg * 8 + i) * 64 + (((row >> 3) ^ i ^ seg)) * 8 + (row & 7)] = e8[i];
  }
  __syncthreads();  // Q frags in regs (drained above); qps now free for ps

  __hip_bfloat16* psh = qps + w * 1024;         // wave-private, hi tile
  __hip_bfloat16* psl = qps + 4096 + w * 1024;  // wave-private, lo tile
  float m_hi[4] = {-1e30f, -1e30f, -1e30f, -1e30f}, l_hi[4] = {0, 0, 0, 0};
  float m_lo[4] = {-1e30f, -1e30f, -1e30f, -1e30f}, l_lo[4] = {0, 0, 0, 0};
  f32x4 o_hi[4] = {}, o_lo[4] = {};
  int cur = 0;

  // one q-tile update against ks[cur]/vts[cur]
  auto process = [&](const bf16x8& qa0, const bf16x8& qa1, bool diag,
                     float* m_run, float* l_run, f32x4* o, __hip_bfloat16* psw) {
    f32x4 s4[4] = {};
#pragma unroll
    for (int n = 0; n < 4; ++n) {
      const int kr = n * 16 + lr;
      bf16x8 k0f = *(const bf16x8*)(ks[cur] + kr * 64 + ((lg) ^ sw) * 8);
      bf16x8 k1f = *(const bf16x8*)(ks[cur] + kr * 64 + ((4 + lg) ^ sw) * 8);
      s4[n] = __builtin_amdgcn_mfma_f32_16x16x32_bf16(qa0, k0f, s4[n], 0, 0, 0);
      s4[n] = __builtin_amdgcn_mfma_f32_16x16x32_bf16(qa1, k1f, s4[n], 0, 0, 0);
    }
    float p[4][4], mloc[4];
#pragma unroll
    for (int j = 0; j < 4; ++j) {
      float mm = -1e30f;
#pragma unroll
      for (int n = 0; n < 4; ++n) {
        float v = s4[n][j] * 0.125f;
        if (diag && (n * 16 + lr) > (w * 16 + lg * 4 + j)) v = -1e30f;
        p[n][j] = v;
        mm = fmaxf(mm, v);
      }
      mloc[j] = mm;
    }
#pragma unroll
    for (int off = 1; off < 16; off <<= 1)
#pragma unroll
      for (int j = 0; j < 4; ++j)
        mloc[j] = fmaxf(mloc[j], __shfl_xor(mloc[j], off, 16));
    float sc[4], ls[4];
#pragma unroll
    for (int j = 0; j < 4; ++j) {
      float mn = fmaxf(m_run[j], mloc[j]);
      sc[j] = __expf(m_run[j] - mn);
      m_run[j] = mn;
      float s = 0.f;
#pragma unroll
      for (int n = 0; n < 4; ++n) { p[n][j] = __expf(p[n][j] - mn); s += p[n][j]; }
      ls[j] = s;
    }
#pragma unroll
    for (int off = 1; off < 16; off <<= 1)
#pragma unroll
      for (int j = 0; j < 4; ++j) ls[j] += __shfl_xor(ls[j], off, 16);
#pragma unroll
    for (int j = 0; j < 4; ++j) l_run[j] = l_run[j] * sc[j] + ls[j];
#pragma unroll
    for (int n = 0; n < 4; ++n)
#pragma unroll
      for (int j = 0; j < 4; ++j) o[n][j] *= sc[j];
#pragma unroll
    for (int n = 0; n < 4; ++n)
#pragma unroll
      for (int j = 0; j < 4; ++j) {
        const int prow = lg * 4 + j;
        const int phys = (n * 2 + (lr >> 3)) ^ (prow & 7);
        psw[prow * 64 + phys * 8 + (lr & 7)] = __float2bfloat16(p[n][j]);
      }
    bf16x8 pa0 = *(const bf16x8*)(&psw[lr * 64 + ((lg) ^ sw) * 8]);
    bf16x8 pa1 = *(const bf16x8*)(&psw[lr * 64 + ((4 + lg) ^ sw) * 8]);
#pragma unroll
    for (int n = 0; n < 4; ++n) {
      const int vdh = n * 16 + lr;
      const int swv = (vdh & 7) ^ ((vdh >> 3) & 7);
      bf16x8 v0f = *(const bf16x8*)(vts[cur] + vdh * 64 + ((lg) ^ swv) * 8);
      bf16x8 v1f = *(const bf16x8*)(vts[cur] + vdh * 64 + ((4 + lg) ^ swv) * 8);
      o[n] = __builtin_amdgcn_mfma_f32_16x16x32_bf16(pa0, v0f, o[n], 0, 0, 0);
      o[n] = __builtin_amdgcn_mfma_f32_16x16x32_bf16(pa1, v1f, o[n], 0, 0, 0);
    }
  };

  for (int kvt = 0; kvt <= qhi; ++kvt) {
    const int nxt = cur ^ 1;
    const bool pf = (kvt < qhi);
    if (pf) {  // prefetch next K tile + V rows
      const int kv1 = (kvt + 1) * 64;
#pragma unroll
      for (int r = 0; r < 2; ++r) {
        int c = tid + r * 256, row = c >> 3, p = c & 7;
        GLD16(kb + (size_t)(kv1 + row) * rs + (p ^ (row & 7)) * 8, ks[nxt] + c * 8);
        vreg[r] = *(const float4*)(vb + (size_t)(kv1 + row) * rs + p * 8);
      }
    }
    process(qh0, qh1, kvt == qhi, m_hi, l_hi, o_hi, psh);
    if (kvt <= qlo) process(ql0, ql1, kvt == qlo, m_lo, l_lo, o_lo, psl);
    if (pf) {  // write V(t+1) regs -> vts[nxt] (vmcnt wait after compute)
#pragma unroll
      for (int r = 0; r < 2; ++r) {
        int c = tid + r * 256, row = c >> 3, seg = c & 7;
        const __hip_bfloat16* e8 = (const __hip_bfloat16*)&vreg[r];
#pragma unroll
        for (int i = 0; i < 8; ++i)
          vts[nxt][(seg * 8 + i) * 64 + (((row >> 3) ^ i ^ seg)) * 8 + (row & 7)] = e8[i];
      }
    }
    __syncthreads();
    cur = nxt;
  }
#pragma unroll
  for (int j = 0; j < 4; ++j) {
    float invh = 1.0f / l_hi[j], invl = 1.0f / l_lo[j];
    size_t rowh = (size_t)b * 2048 + q0hi + w * 16 + lg * 4 + j;
    size_t rowl = (size_t)b * 2048 + q0lo + w * 16 + lg * 4 + j;
#pragma unroll
    for (int n = 0; n < 4; ++n) {
      outp[rowh * 1024 + h * 64 + n * 16 + lr] = o_hi[n][j] * invh;
      outp[rowl * 1024 + h * 64 + n * 16 + lr] = o_lo[n][j] * invl;
    }
  }
}

extern "C" void kernel_launch(void* const* d_in, const int* in_sizes, int n_in,
                              void* d_out, int out_size, void* d_ws, size_t ws_size,
                              hipStream_t stream) {
  const float* x     = (const float*)d_in[0];
  const float* Wqkv0 = (const float*)d_in[1];
  const float* bqkv0 = (const float*)d_in[2];
  const float* Wqkv1 = (const float*)d_in[3];
  const float* bqkv1 = (const float*)d_in[4];
  const float* Wg    = (const float*)d_in[5];
  const float* bg    = (const float*)d_in[6];
  const float* Wo    = (const float*)d_in[7];
  const float* bo    = (const float*)d_in[8];
  float* out = (float*)d_out;

  char* ws = (char*)d_ws;
  __hip_bfloat16* xb   = (__hip_bfloat16*)(ws);              // 8 MB (x_bf16 -> residb -> preout)
  __hip_bfloat16* qkv  = (__hip_bfloat16*)(ws + 8388608);    // 24 MB (qkv0 then qkv1)
  float*          pred = (float*)(ws + 33554432);            // 16 MB
  float*          corr = (float*)(ws + 50331648);            // 16 MB
  __hip_bfloat16* catb = (__hip_bfloat16*)(ws + 67108864);   // 16 MB [pred | corr] bf16
  __hip_bfloat16* Wt0  = (__hip_bfloat16*)(ws + 83886080);   // 6 MB
  __hip_bfloat16* Wt1  = (__hip_bfloat16*)(ws + 90177536);   // 6 MB
  __hip_bfloat16* Wgt  = (__hip_bfloat16*)(ws + 96468992);   // 4 MB
  __hip_bfloat16* Wot  = (__hip_bfloat16*)(ws + 100663296);  // 2 MB  (total ~98 MB)

  dim3 tb(32, 8);
  transpose_cast<<<dim3(3072 / 32, 1024 / 32), tb, 0, stream>>>(Wqkv0, Wt0, 1024, 3072);
  transpose_cast<<<dim3(3072 / 32, 1024 / 32), tb, 0, stream>>>(Wqkv1, Wt1, 1024, 3072);
  transpose_cast<<<dim3(1024 / 32, 2048 / 32), tb, 0, stream>>>(Wg, Wgt, 2048, 1024);
  transpose_cast<<<dim3(1024 / 32, 1024 / 32), tb, 0, stream>>>(Wo, Wot, 1024, 1024);
  cast_f32_bf16<<<4096, 256, 0, stream>>>(x, xb);

  // qkv0 = x @ Wqkv0 + b
  gemm_bf16<0><<<dim3(24, 32), 256, 0, stream>>>(xb, Wt0, bqkv0, (void*)qkv,
                                                 nullptr, nullptr, 4096, 3072, 1024);
  attn_kernel<<<dim3(16, 16, 2), 256, 0, stream>>>(qkv, pred);
  resid_cast<<<4096, 256, 0, stream>>>(x, pred, catb, xb);
  // qkv1 = (x - pred) @ Wqkv1 + b
  gemm_bf16<0><<<dim3(24, 32), 256, 0, stream>>>(xb, Wt1, bqkv1, (void*)qkv,
                                                 nullptr, nullptr, 4096, 3072, 1024);
  attn_kernel<<<dim3(16, 16, 2), 256, 0, stream>>>(qkv, corr);
  corr_cast<<<4096, 256, 0, stream>>>(corr, catb);
  // preout = sigmoid(cat @ Wg + bg) * corr + pred   (into xb)
  gemm_bf16<1><<<dim3(8, 32), 256, 0, stream>>>(catb, Wgt, bg, (void*)xb,
                                                corr, pred, 4096, 1024, 2048);
  // out = preout @ Wo + bo (fp32)
  gemm_bf16<2><<<dim3(8, 32), 256, 0, stream>>>(xb, Wot, bo, (void*)out,
                                                nullptr, nullptr, 4096, 1024, 1024);
}